// Round 20
// baseline (6083.288 us; speedup 1.0000x reference)
//
#include <hip/hip_runtime.h>

#define TDIM 16

// repack OIHW (fp32) -> [ic*K*K][oc]
template<int OC>
__global__ __launch_bounds__(256) void repack_k(const float* __restrict__ w,
                                                float* __restrict__ wT, int tot) {
  int i = blockIdx.x * 256 + threadIdx.x;
  if (i >= tot) return;
  int row = i / OC, oc = i - row * OC;          // row = ic*K*K + ky*K + kx
  wT[i] = w[(size_t)oc * (size_t)(tot / OC) + row];
}

// repack OIHW (fp32) -> [slice][ic*K*K][OCH]  (slice = oc/OCH, contiguous)
template<int OCTOT, int OCH>
__global__ __launch_bounds__(256) void repack_sl(const float* __restrict__ w,
                                                 float* __restrict__ wT,
                                                 int ickk) {
  int tot = OCTOT * ickk;
  int i = blockIdx.x * 256 + threadIdx.x;
  if (i >= tot) return;
  int per = ickk * OCH;
  int slice = i / per;
  int rem = i - slice * per;
  int row = rem / OCH, och = rem - row * OCH;
  wT[i] = w[(size_t)(slice * OCH + och) * ickk + row];
}

// e2[r] = sum_f32 e*e
__global__ __launch_bounds__(256) void e2_k(const float* __restrict__ emb,
                                            float* __restrict__ e2) {
  int r = blockIdx.x * 256 + threadIdx.x;
  if (r >= 512) return;
  float s = 0.f;
#pragma unroll
  for (int d = 0; d < 64; ++d) s = fmaf(emb[r * 64 + d], emb[r * 64 + d], s);
  e2[r] = s;
}

// 1-px direct conv (R14-proven): fp32, bias in acc, LDS weights.
template<int IC, int OCTOT, int OCH, int K, int S, int PAD, int CCH,
         int IH, int IW, bool RELU_IN, bool RELU_OUT>
__global__ __launch_bounds__(256) void conv_direct(
    const float* __restrict__ in, const float* __restrict__ wT,
    const float* __restrict__ bias, float* __restrict__ out) {
  constexpr int OH = (IH + 2 * PAD - K) / S + 1;
  constexpr int OW = OH;
  constexpr int RS = (TDIM - 1) * S + K;
  constexpr int CS = RS;
  constexpr int TX = OW / TDIM;
  constexpr int TILES = TX * TX;
  constexpr int TOT = CCH * RS * CS;
  constexpr int WSLAB = CCH * K * K * OCH;

  __shared__ __align__(16) float lds[TOT];
  __shared__ __align__(16) float wlds[WSLAB];

  const int tid = threadIdx.x;
  const int n = blockIdx.y;
  const int tile = blockIdx.x % TILES;
  const int oc0 = (blockIdx.x / TILES) * OCH;
  const int oh0 = (tile / TX) * TDIM;
  const int ow0 = (tile % TX) * TDIM;
  const int ty = tid >> 4, tx = tid & 15;
  const int oh = oh0 + ty, ow = ow0 + tx;

  float acc[OCH];
#pragma unroll
  for (int oc = 0; oc < OCH; ++oc) acc[oc] = bias[oc0 + oc];

  for (int ic0 = 0; ic0 < IC; ic0 += CCH) {
    __syncthreads();
    for (int i = tid; i < TOT; i += 256) {
      int c = i / (RS * CS);
      int rem = i - c * (RS * CS);
      int r = rem / CS;
      int col = rem - r * CS;
      int gr = oh0 * S + r - PAD;
      int gc = ow0 * S + col - PAD;
      float v = 0.f;
      if (gr >= 0 && gr < IH && gc >= 0 && gc < IW) {
        v = in[((size_t)(n * IC + ic0 + c) * IH + gr) * IW + gc];
        if (RELU_IN) v = fmaxf(v, 0.f);
      }
      lds[i] = v;
    }
    {
      const float* wsrc = wT + (size_t)ic0 * (K * K * OCTOT) + oc0;
      for (int i = tid; i < WSLAB; i += 256) {
        int row = i / OCH, c = i - row * OCH;
        wlds[i] = wsrc[(size_t)row * OCTOT + c];
      }
    }
    __syncthreads();
#pragma unroll 1
    for (int c = 0; c < CCH; ++c) {
#pragma unroll
      for (int ky = 0; ky < K; ++ky)
#pragma unroll
        for (int kx = 0; kx < K; ++kx) {
          float v = lds[(c * RS + ty * S + ky) * CS + tx * S + kx];
          const float4* w4 =
              (const float4*)(wlds + (c * K * K + ky * K + kx) * OCH);
#pragma unroll
          for (int q = 0; q < OCH / 4; ++q) {
            float4 wv = w4[q];
            acc[4 * q + 0] = fmaf(wv.x, v, acc[4 * q + 0]);
            acc[4 * q + 1] = fmaf(wv.y, v, acc[4 * q + 1]);
            acc[4 * q + 2] = fmaf(wv.z, v, acc[4 * q + 2]);
            acc[4 * q + 3] = fmaf(wv.w, v, acc[4 * q + 3]);
          }
        }
    }
  }

#pragma unroll
  for (int oc = 0; oc < OCH; ++oc) {
    float r = acc[oc];
    if (RELU_OUT) r = fmaxf(r, 0.f);
    out[((size_t)(n * OCTOT + oc0 + oc) * OH + oh) * OW + ow] = r;
  }
}

// 4-px register-blocked conv, input-only LDS double-buffer (T14 async),
// weights read UNIFORMLY from global (scalar-load path, no LDS, no VGPR).
// Weight layout [slice][ic*K*K][OCH]. FMA order per output unchanged.
template<int IC, int OCTOT, int OCH, int K, int S, int PAD, int CCH,
         int IH, int IW, bool RELU_IN, bool RELU_OUT>
__global__ __launch_bounds__(256, 1) void conv_p4s(
    const float* __restrict__ in, const float* __restrict__ wT,
    const float* __restrict__ bias, float* __restrict__ out) {
  constexpr int OH = (IH + 2 * PAD - K) / S + 1;
  constexpr int OW = OH;
  constexpr int TR = 32, TC = 32;
  constexpr int RS = (TR - 1) * S + K;
  constexpr int CSR = (TC - 1) * S + K;
  constexpr int CS = (CSR + 3) & ~3;
  constexpr int TX = OW / TC;
  constexpr int TILES = (OH / TR) * TX;
  constexpr int TOT = CCH * RS * CS;
  constexpr int NSTG = (TOT + 255) / 256;
  constexpr int NCH = IC / CCH;
  constexpr int VW = ((3 * S + K) + 3) & ~3;

  __shared__ __align__(16) float lds[2][TOT];

  const int tid = threadIdx.x;
  const int n = blockIdx.y;
  const int tile = blockIdx.x % TILES;
  const int slice = blockIdx.x / TILES;
  const int oc0 = slice * OCH;
  const int oh0 = (tile / TX) * TR;
  const int ow0 = (tile % TX) * TC;
  const int r = tid >> 3;
  const int c0 = (tid & 7) * 4;

  // uniform weight slab base for this slice
  const float* __restrict__ wslab = wT + (size_t)slice * (IC * K * K * OCH);

  float acc[4][OCH];
#pragma unroll
  for (int oc = 0; oc < OCH; ++oc) {
    float b = bias[oc0 + oc];
    acc[0][oc] = b; acc[1][oc] = b; acc[2][oc] = b; acc[3][oc] = b;
  }

  float tmp[NSTG];

  auto loadc = [&](int ic0) {
#pragma unroll
    for (int s = 0; s < NSTG; ++s) {
      int i = s * 256 + tid;
      float v = 0.f;
      if (i < TOT) {
        int cc = i / (RS * CS);
        int rem = i - cc * (RS * CS);
        int rr = rem / CS;
        int col = rem - rr * CS;
        int gr = oh0 * S + rr - PAD;
        int gc = ow0 * S + col - PAD;
        if (gr >= 0 && gr < IH && gc >= 0 && gc < IW) {
          v = in[((size_t)(n * IC + ic0 + cc) * IH + gr) * IW + gc];
          if (RELU_IN) v = fmaxf(v, 0.f);
        }
      }
      tmp[s] = v;
    }
  };
  auto writec = [&](int b) {
#pragma unroll
    for (int s = 0; s < NSTG; ++s) {
      int i = s * 256 + tid;
      if (i < TOT) lds[b][i] = tmp[s];
    }
  };

  loadc(0);
  writec(0);
  __syncthreads();

  int cur = 0;
#pragma unroll 1
  for (int ch = 0; ch < NCH; ++ch) {
    if (ch + 1 < NCH) loadc((ch + 1) * CCH);   // next-chunk loads in flight

    const float* L = lds[cur];
#pragma unroll 1
    for (int c = 0; c < CCH; ++c) {
      const int crow = (ch * CCH + c) * (K * K);
#pragma unroll
      for (int ky = 0; ky < K; ++ky) {
        float vwin[VW];
        const float* vrow = L + (c * RS + r * S + ky) * CS + c0 * S;
#pragma unroll
        for (int q = 0; q < VW / 4; ++q) {
          float4 t = ((const float4*)vrow)[q];
          vwin[4 * q + 0] = t.x; vwin[4 * q + 1] = t.y;
          vwin[4 * q + 2] = t.z; vwin[4 * q + 3] = t.w;
        }
#pragma unroll
        for (int kx = 0; kx < K; ++kx) {
          const float4* w4 =
              (const float4*)(wslab + (size_t)(crow + ky * K + kx) * OCH);
#pragma unroll
          for (int q = 0; q < OCH / 4; ++q) {
            float4 wv = w4[q];          // uniform address -> scalar load
#pragma unroll
            for (int p = 0; p < 4; ++p) {
              acc[p][4 * q + 0] = fmaf(wv.x, vwin[p * S + kx], acc[p][4 * q + 0]);
              acc[p][4 * q + 1] = fmaf(wv.y, vwin[p * S + kx], acc[p][4 * q + 1]);
              acc[p][4 * q + 2] = fmaf(wv.z, vwin[p * S + kx], acc[p][4 * q + 2]);
              acc[p][4 * q + 3] = fmaf(wv.w, vwin[p * S + kx], acc[p][4 * q + 3]);
            }
          }
        }
      }
    }

    if (ch + 1 < NCH) writec(cur ^ 1);
    __syncthreads();
    cur ^= 1;
  }

  const int oh = oh0 + r, ow = ow0 + c0;
#pragma unroll
  for (int oc = 0; oc < OCH; ++oc) {
    float4 o;
    o.x = acc[0][oc]; o.y = acc[1][oc]; o.z = acc[2][oc]; o.w = acc[3][oc];
    if (RELU_OUT) {
      o.x = fmaxf(o.x, 0.f); o.y = fmaxf(o.y, 0.f);
      o.z = fmaxf(o.z, 0.f); o.w = fmaxf(o.w, 0.f);
    }
    *(float4*)(out + ((size_t)(n * OCTOT + oc0 + oc) * OH + oh) * OW + ow) = o;
  }
}

// 1x1 conv (relu on read) + residual add, fp32; weights staged in LDS. (R14)
template<int IC, int OC>
__global__ __launch_bounds__(256) void conv1x1_res(
    const float* __restrict__ in, const float* __restrict__ wT,
    const float* __restrict__ bias, const float* __restrict__ res,
    float* __restrict__ out) {
  __shared__ __align__(16) float wlds[IC * OC];
  for (int i = threadIdx.x; i < IC * OC; i += 256) wlds[i] = wT[i];
  __syncthreads();

  const int pid = blockIdx.x * 256 + threadIdx.x;
  const int n = pid >> 12, px = pid & 4095;
  const float* ip = in + (size_t)n * IC * 4096 + px;
  float acc[OC];
#pragma unroll
  for (int o = 0; o < OC; ++o) acc[o] = bias[o];
#pragma unroll 4
  for (int i = 0; i < IC; ++i) {
    float v = fmaxf(ip[(size_t)i * 4096], 0.f);
    const float4* w4 = (const float4*)(wlds + i * OC);
#pragma unroll
    for (int q = 0; q < OC / 4; ++q) {
      float4 wv = w4[q];
      acc[4 * q + 0] = fmaf(wv.x, v, acc[4 * q + 0]);
      acc[4 * q + 1] = fmaf(wv.y, v, acc[4 * q + 1]);
      acc[4 * q + 2] = fmaf(wv.z, v, acc[4 * q + 2]);
      acc[4 * q + 3] = fmaf(wv.w, v, acc[4 * q + 3]);
    }
  }
  const float* rp = res + (size_t)n * OC * 4096 + px;
  float* op = out + (size_t)n * OC * 4096 + px;
#pragma unroll
  for (int o = 0; o < OC; ++o) op[(size_t)o * 4096] = rp[(size_t)o * 4096] + acc[o];
}

// Fused conv4 + VQ (R14). LDS-staged wT4/e2/emb-chunks; BHWD gather.
__global__ __launch_bounds__(256) void conv4_vq(
    const float* __restrict__ h, const float* __restrict__ wT4,
    const float* __restrict__ b4, const float* __restrict__ emb,
    const float* __restrict__ e2, float* __restrict__ out) {
  __shared__ __align__(16) float wlds[128 * 64];
  __shared__ __align__(16) float elds[64 * 64];
  __shared__ float e2lds[512];

  const int tid = threadIdx.x;
  for (int i = tid; i < 128 * 64; i += 256) wlds[i] = wT4[i];
  for (int i = tid; i < 512; i += 256) e2lds[i] = e2[i];
  __syncthreads();

  const int pid = blockIdx.x * 256 + tid;
  const int n = pid >> 12, px = pid & 4095;
  const float* ip = h + (size_t)n * 128 * 4096 + px;
  float z[64];
#pragma unroll
  for (int d = 0; d < 64; ++d) z[d] = b4[d];
#pragma unroll 2
  for (int i = 0; i < 128; ++i) {
    float v = fmaxf(ip[(size_t)i * 4096], 0.f);
    const float4* w4 = (const float4*)(wlds + i * 64);
#pragma unroll
    for (int q = 0; q < 16; ++q) {
      float4 wv = w4[q];
      z[4 * q + 0] = fmaf(wv.x, v, z[4 * q + 0]);
      z[4 * q + 1] = fmaf(wv.y, v, z[4 * q + 1]);
      z[4 * q + 2] = fmaf(wv.z, v, z[4 * q + 2]);
      z[4 * q + 3] = fmaf(wv.w, v, z[4 * q + 3]);
    }
  }
  float z2 = 0.f;
#pragma unroll
  for (int d = 0; d < 64; ++d) z2 = fmaf(z[d], z[d], z2);

  float best = __builtin_inff();
  int bidx = 0;
  for (int r0 = 0; r0 < 512; r0 += 64) {
    __syncthreads();
    for (int i = tid; i < 64 * 64; i += 256) elds[i] = emb[(size_t)r0 * 64 + i];
    __syncthreads();
#pragma unroll 1
    for (int r = 0; r < 64; ++r) {
      const float4* e4 = (const float4*)(elds + r * 64);
      float p0 = 0.f, p1 = 0.f, p2 = 0.f, p3 = 0.f;
#pragma unroll
      for (int q = 0; q < 16; ++q) {
        float4 ev = e4[q];
        p0 = fmaf(ev.x, z[4 * q + 0], p0);
        p1 = fmaf(ev.y, z[4 * q + 1], p1);
        p2 = fmaf(ev.z, z[4 * q + 2], p2);
        p3 = fmaf(ev.w, z[4 * q + 3], p3);
      }
      float dot = (p0 + p1) + (p2 + p3);
      float dist = (z2 - 2.f * dot) + e2lds[r0 + r];
      if (dist < best) { best = dist; bidx = r0 + r; }
    }
  }

  const float4* eb = (const float4*)(emb + (size_t)bidx * 64);
  float4* op = (float4*)(out + (size_t)pid * 64);
#pragma unroll
  for (int q = 0; q < 16; ++q) op[q] = eb[q];
}

extern "C" void kernel_launch(void* const* d_in, const int* in_sizes, int n_in,
                              void* d_out, int out_size, void* d_ws, size_t ws_size,
                              hipStream_t stream) {
  const float* x    = (const float*)d_in[0];
  const float* w1   = (const float*)d_in[1];
  const float* b1   = (const float*)d_in[2];
  const float* w2   = (const float*)d_in[3];
  const float* b2   = (const float*)d_in[4];
  const float* w3   = (const float*)d_in[5];
  const float* b3   = (const float*)d_in[6];
  const float* r1w1 = (const float*)d_in[7];
  const float* r1b1 = (const float*)d_in[8];
  const float* r1w2 = (const float*)d_in[9];
  const float* r1b2 = (const float*)d_in[10];
  const float* r2w1 = (const float*)d_in[11];
  const float* r2b1 = (const float*)d_in[12];
  const float* r2w2 = (const float*)d_in[13];
  const float* r2b2 = (const float*)d_in[14];
  const float* w4   = (const float*)d_in[15];
  const float* b4   = (const float*)d_in[16];
  const float* emb  = (const float*)d_in[17];

  char* ws = (char*)d_ws;
  float* wT1   = (float*)ws;         // 1024
  float* wT2   = wT1 + 1024;         // 131072  [slice][row][32]
  float* wT3   = wT2 + 131072;       // 147456  [slice][row][32]
  float* wTr1a = wT3 + 147456;       // 36864
  float* wTr1b = wTr1a + 36864;      // 4096
  float* wTr2a = wTr1b + 4096;       // 36864
  float* wTr2b = wTr2a + 36864;      // 4096
  float* wT4   = wTr2b + 4096;       // 8192
  float* e2v   = wT4 + 8192;         // 512

  const size_t WOFF = 2ull << 20;
  const size_t SZ_A = 4194304ull;    // 64ch*128*128*4 (h1/h3/h5)
  const size_t SZ_B = 2097152ull;    // 128ch*64*64*4  (h2/h4)
  const size_t SZ_C = 524288ull;     // 32ch*64*64*4   (t32)
  const size_t PER_IMG = SZ_A + SZ_B + SZ_C;
  int NB = 64;
  while (NB > 1 && WOFF + (size_t)NB * PER_IMG > ws_size) NB >>= 1;

  char* bufs = ws + WOFF;
  float* A  = (float*)bufs;
  float* B_ = (float*)(bufs + (size_t)NB * SZ_A);
  float* C_ = (float*)(bufs + (size_t)NB * (SZ_A + SZ_B));

  auto blk = [](int tot) { return (tot + 255) / 256; };
  repack_k<64> <<<blk(1024),   256, 0, stream>>>(w1,   wT1,   1024);
  repack_sl<128, 32><<<blk(131072), 256, 0, stream>>>(w2, wT2, 64 * 16);
  repack_sl<128, 32><<<blk(147456), 256, 0, stream>>>(w3, wT3, 128 * 9);
  repack_k<32> <<<blk(36864),  256, 0, stream>>>(r1w1, wTr1a, 36864);
  repack_k<128><<<blk(4096),   256, 0, stream>>>(r1w2, wTr1b, 4096);
  repack_k<32> <<<blk(36864),  256, 0, stream>>>(r2w1, wTr2a, 36864);
  repack_k<128><<<blk(4096),   256, 0, stream>>>(r2w2, wTr2b, 4096);
  repack_k<64> <<<blk(8192),   256, 0, stream>>>(w4,   wT4,   8192);
  e2_k<<<2, 256, 0, stream>>>(emb, e2v);

  for (int n0 = 0; n0 < 64; n0 += NB) {
    const int nb = (64 - n0 < NB) ? (64 - n0) : NB;
    const float* xc = x + (size_t)n0 * 65536;               // (nb,1,256,256)
    float* oc = (float*)d_out + (size_t)n0 * 4096 * 64;     // BHWD chunk base

    // conv1: 1px, OC=64 whole (R14 config)
    conv_direct<1, 64, 64, 4, 2, 1, 1, 256, 256, false, true>
        <<<dim3(64, nb), 256, 0, stream>>>(xc, wT1, b1, A);
    // conv2: 4px, scalar weights, input dbuf CCH=1; 4 tiles x 4 slices
    conv_p4s<64, 128, 32, 4, 2, 1, 1, 128, 128, false, true>
        <<<dim3(16, nb), 256, 0, stream>>>(A, wT2, b2, B_);
    // conv3: 4px, scalar weights, input dbuf CCH=4; 4 tiles x 4 slices
    conv_p4s<128, 128, 32, 3, 1, 1, 4, 64, 64, false, false>
        <<<dim3(16, nb), 256, 0, stream>>>(B_, wT3, b3, A);
    // res1: 1px, OC=32 whole, CCH=8 (R14 config)
    conv_direct<128, 32, 32, 3, 1, 1, 8, 64, 64, true, false>
        <<<dim3(16, nb), 256, 0, stream>>>(A, wTr1a, r1b1, C_);
    conv1x1_res<32, 128><<<nb * 16, 256, 0, stream>>>(C_, wTr1b, r1b2, A, B_);
    // res2
    conv_direct<128, 32, 32, 3, 1, 1, 8, 64, 64, true, false>
        <<<dim3(16, nb), 256, 0, stream>>>(B_, wTr2a, r2b1, C_);
    conv1x1_res<32, 128><<<nb * 16, 256, 0, stream>>>(C_, wTr2b, r2b2, B_, A);
    // conv4 + VQ
    conv4_vq<<<nb * 16, 256, 0, stream>>>(A, wT4, b4, emb, e2v, oc);
  }
}

// Round 22
// 3306.614 us; speedup vs baseline: 1.8397x; 1.8397x over previous
//
#include <hip/hip_runtime.h>

#define TDIM 16

typedef unsigned short u16;
typedef __attribute__((ext_vector_type(8))) short bf16x8;
typedef __attribute__((ext_vector_type(4))) float f32x4;

__device__ __forceinline__ float b2f(u16 u) {
  return __uint_as_float(((unsigned)u) << 16);
}
__device__ __forceinline__ u16 f2bf(float f) {
  unsigned u = __float_as_uint(f);
  unsigned r = 0x7FFFu + ((u >> 16) & 1u);
  return (u16)((u + r) >> 16);
}

// repack OIHW (fp32) -> [ic*K*K][oc]
template<int OC>
__global__ __launch_bounds__(256) void repack_k(const float* __restrict__ w,
                                                float* __restrict__ wT, int tot) {
  int i = blockIdx.x * 256 + threadIdx.x;
  if (i >= tot) return;
  int row = i / OC, oc = i - row * OC;          // row = ic*K*K + ky*K + kx
  wT[i] = w[(size_t)oc * (size_t)(tot / OC) + row];
}

// repack OIHW(3x3) fp32 -> 3 bf16 limbs, layout [pos][ic-chunk][oc][32]
template<int OC, int IC>
__global__ __launch_bounds__(256) void repack_mf3(const float* __restrict__ w,
                                                  short* __restrict__ hi,
                                                  short* __restrict__ mid,
                                                  short* __restrict__ lo) {
  constexpr int NCH = IC / 32;
  int tot = OC * IC * 9;
  int i = blockIdx.x * 256 + threadIdx.x;
  if (i >= tot) return;
  int icl = i & 31;
  int rem = i >> 5;
  int oc = rem % OC; rem /= OC;
  int ch = rem % NCH;
  int pos = rem / NCH;
  int ic = ch * 32 + icl;
  int ky = pos / 3, kx = pos - ky * 3;
  float v = w[((size_t)(oc * IC + ic) * 3 + ky) * 3 + kx];
  u16 h = f2bf(v);
  float t1 = v - b2f(h);
  u16 m = f2bf(t1);
  float t2 = t1 - b2f(m);
  hi[i] = (short)h;
  mid[i] = (short)m;
  lo[i] = (short)f2bf(t2);
}

// e2[r] = sum_f32 e*e
__global__ __launch_bounds__(256) void e2_k(const float* __restrict__ emb,
                                            float* __restrict__ e2) {
  int r = blockIdx.x * 256 + threadIdx.x;
  if (r >= 512) return;
  float s = 0.f;
#pragma unroll
  for (int d = 0; d < 64; ++d) s = fmaf(emb[r * 64 + d], emb[r * 64 + d], s);
  e2[r] = s;
}

// MFMA 3-limb bf16 6-pass 3x3 conv (IC=128, 64x64, pad 1, stride 1).
// OC = MT*16. 2 output rows/block, 4 waves, each wave: 2 px-tiles x MT.
// x limbs staged in LDS per 32-ic chunk; w limb fragments loaded from
// global (coalesced 16B/lane) per (pos,chunk). fp32 acc; bias in epilogue.
template<int MT, bool RELU_IN>
__global__ __launch_bounds__(256, 2) void conv_mf3(
    const float* __restrict__ in, const short* __restrict__ wh,
    const short* __restrict__ wm, const short* __restrict__ wl,
    const float* __restrict__ bias, float* __restrict__ out) {
  constexpr int OC = MT * 16;
  __shared__ __align__(16) short xh[10560];   // [4 rows][66 cols][40 stride]
  __shared__ __align__(16) short xm[10560];
  __shared__ __align__(16) short xl[10560];

  const int tid = threadIdx.x;
  const int n = blockIdx.y;
  const int r0 = blockIdx.x * 2;
  const int wv = tid >> 6, lane = tid & 63;
  const int nlo = lane & 15, kg = lane >> 4;

  f32x4 acc[MT][2];
#pragma unroll
  for (int mt = 0; mt < MT; ++mt)
#pragma unroll
    for (int ti = 0; ti < 2; ++ti) acc[mt][ti] = (f32x4){0.f, 0.f, 0.f, 0.f};

#pragma unroll 1
  for (int ch = 0; ch < 4; ++ch) {
    __syncthreads();
    for (int i = tid; i < 8448; i += 256) {
      int c = i % 66;
      int rem = i / 66;
      int lr = rem & 3, icl = rem >> 2;
      int gr = r0 - 1 + lr, gc = c - 1;
      float v = 0.f;
      if (gr >= 0 && gr < 64 && gc >= 0 && gc < 64)
        v = in[((size_t)(n * 128 + ch * 32 + icl) * 64 + gr) * 64 + gc];
      if (RELU_IN) v = fmaxf(v, 0.f);
      u16 h = f2bf(v);
      float t1 = v - b2f(h);
      u16 m = f2bf(t1);
      float t2 = t1 - b2f(m);
      int a = (lr * 66 + c) * 40 + icl;
      xh[a] = (short)h;
      xm[a] = (short)m;
      xl[a] = (short)f2bf(t2);
    }
    __syncthreads();

#pragma unroll 1
    for (int pos = 0; pos < 9; ++pos) {
      const int ky = pos / 3, kx = pos - ky * 3;
      bf16x8 bh[2], bm[2], bl[2];
#pragma unroll
      for (int ti = 0; ti < 2; ++ti) {
        int t = wv * 2 + ti;
        int lr = (t >> 2) + ky;
        int c = (t & 3) * 16 + nlo + kx;
        int a = (lr * 66 + c) * 40 + kg * 8;
        bh[ti] = *(const bf16x8*)(xh + a);
        bm[ti] = *(const bf16x8*)(xm + a);
        bl[ti] = *(const bf16x8*)(xl + a);
      }
      const size_t wo =
          ((size_t)(pos * 4 + ch) * OC + nlo) * 32 + (size_t)kg * 8;
#pragma unroll
      for (int mt = 0; mt < MT; ++mt) {
        const size_t o = wo + (size_t)mt * 16 * 32;
        bf16x8 AH = *(const bf16x8*)(wh + o);
        bf16x8 AM = *(const bf16x8*)(wm + o);
        bf16x8 AL = *(const bf16x8*)(wl + o);
#pragma unroll
        for (int ti = 0; ti < 2; ++ti) {
          acc[mt][ti] = __builtin_amdgcn_mfma_f32_16x16x32_bf16(
              AH, bh[ti], acc[mt][ti], 0, 0, 0);
          acc[mt][ti] = __builtin_amdgcn_mfma_f32_16x16x32_bf16(
              AH, bm[ti], acc[mt][ti], 0, 0, 0);
          acc[mt][ti] = __builtin_amdgcn_mfma_f32_16x16x32_bf16(
              AM, bh[ti], acc[mt][ti], 0, 0, 0);
          acc[mt][ti] = __builtin_amdgcn_mfma_f32_16x16x32_bf16(
              AH, bl[ti], acc[mt][ti], 0, 0, 0);
          acc[mt][ti] = __builtin_amdgcn_mfma_f32_16x16x32_bf16(
              AL, bh[ti], acc[mt][ti], 0, 0, 0);
          acc[mt][ti] = __builtin_amdgcn_mfma_f32_16x16x32_bf16(
              AM, bm[ti], acc[mt][ti], 0, 0, 0);
        }
      }
    }
  }

  // D: col=lane&15 (px), row=(lane>>4)*4+j (oc); + bias
#pragma unroll
  for (int mt = 0; mt < MT; ++mt)
#pragma unroll
    for (int ti = 0; ti < 2; ++ti) {
      int t = wv * 2 + ti;
      int grow = r0 + (t >> 2);
      int px = (t & 3) * 16 + nlo;
#pragma unroll
      for (int j = 0; j < 4; ++j) {
        int oc = mt * 16 + kg * 4 + j;
        out[((size_t)(n * OC + oc) * 64 + grow) * 64 + px] =
            acc[mt][ti][j] + bias[oc];
      }
    }
}

// 1-px direct conv (R14): fp32, bias in acc, LDS weights, full OC.
template<int IC, int OC, int K, int S, int PAD, int CCH, int IH, int IW,
         bool RELU_IN, bool RELU_OUT>
__global__ __launch_bounds__(256) void conv_direct(
    const float* __restrict__ in, const float* __restrict__ wT,
    const float* __restrict__ bias, float* __restrict__ out) {
  constexpr int OH = (IH + 2 * PAD - K) / S + 1;
  constexpr int OW = OH;
  constexpr int RS = (TDIM - 1) * S + K;
  constexpr int CS = RS;
  constexpr int TX = OW / TDIM;
  constexpr int TOT = CCH * RS * CS;
  constexpr int WSLAB = CCH * K * K * OC;

  __shared__ __align__(16) float lds[TOT];
  __shared__ __align__(16) float wlds[WSLAB];

  const int tid = threadIdx.x;
  const int n = blockIdx.y;
  const int tile = blockIdx.x;
  const int oh0 = (tile / TX) * TDIM;
  const int ow0 = (tile % TX) * TDIM;
  const int ty = tid >> 4, tx = tid & 15;
  const int oh = oh0 + ty, ow = ow0 + tx;

  float acc[OC];
#pragma unroll
  for (int oc = 0; oc < OC; ++oc) acc[oc] = bias[oc];

  for (int ic0 = 0; ic0 < IC; ic0 += CCH) {
    __syncthreads();
    for (int i = tid; i < TOT; i += 256) {
      int c = i / (RS * CS);
      int rem = i - c * (RS * CS);
      int r = rem / CS;
      int col = rem - r * CS;
      int gr = oh0 * S + r - PAD;
      int gc = ow0 * S + col - PAD;
      float v = 0.f;
      if (gr >= 0 && gr < IH && gc >= 0 && gc < IW) {
        v = in[((size_t)(n * IC + ic0 + c) * IH + gr) * IW + gc];
        if (RELU_IN) v = fmaxf(v, 0.f);
      }
      lds[i] = v;
    }
    {
      const float* wsrc = wT + (size_t)ic0 * (K * K * OC);
      for (int i = tid; i < WSLAB; i += 256) wlds[i] = wsrc[i];
    }
    __syncthreads();
#pragma unroll 1
    for (int c = 0; c < CCH; ++c) {
#pragma unroll
      for (int ky = 0; ky < K; ++ky)
#pragma unroll
        for (int kx = 0; kx < K; ++kx) {
          float v = lds[(c * RS + ty * S + ky) * CS + tx * S + kx];
          const float4* w4 =
              (const float4*)(wlds + (c * K * K + ky * K + kx) * OC);
#pragma unroll
          for (int q = 0; q < OC / 4; ++q) {
            float4 wv = w4[q];
            acc[4 * q + 0] = fmaf(wv.x, v, acc[4 * q + 0]);
            acc[4 * q + 1] = fmaf(wv.y, v, acc[4 * q + 1]);
            acc[4 * q + 2] = fmaf(wv.z, v, acc[4 * q + 2]);
            acc[4 * q + 3] = fmaf(wv.w, v, acc[4 * q + 3]);
          }
        }
    }
  }

#pragma unroll
  for (int oc = 0; oc < OC; ++oc) {
    float r = acc[oc];
    if (RELU_OUT) r = fmaxf(r, 0.f);
    out[((size_t)(n * OC + oc) * OH + oh) * OW + ow] = r;
  }
}

// 1x1 conv (relu on read) + residual add, fp32; weights staged in LDS. (R14)
template<int IC, int OC>
__global__ __launch_bounds__(256) void conv1x1_res(
    const float* __restrict__ in, const float* __restrict__ wT,
    const float* __restrict__ bias, const float* __restrict__ res,
    float* __restrict__ out) {
  __shared__ __align__(16) float wlds[IC * OC];
  for (int i = threadIdx.x; i < IC * OC; i += 256) wlds[i] = wT[i];
  __syncthreads();

  const int pid = blockIdx.x * 256 + threadIdx.x;
  const int n = pid >> 12, px = pid & 4095;
  const float* ip = in + (size_t)n * IC * 4096 + px;
  float acc[OC];
#pragma unroll
  for (int o = 0; o < OC; ++o) acc[o] = bias[o];
#pragma unroll 4
  for (int i = 0; i < IC; ++i) {
    float v = fmaxf(ip[(size_t)i * 4096], 0.f);
    const float4* w4 = (const float4*)(wlds + i * OC);
#pragma unroll
    for (int q = 0; q < OC / 4; ++q) {
      float4 wv = w4[q];
      acc[4 * q + 0] = fmaf(wv.x, v, acc[4 * q + 0]);
      acc[4 * q + 1] = fmaf(wv.y, v, acc[4 * q + 1]);
      acc[4 * q + 2] = fmaf(wv.z, v, acc[4 * q + 2]);
      acc[4 * q + 3] = fmaf(wv.w, v, acc[4 * q + 3]);
    }
  }
  const float* rp = res + (size_t)n * OC * 4096 + px;
  float* op = out + (size_t)n * OC * 4096 + px;
#pragma unroll
  for (int o = 0; o < OC; ++o) op[(size_t)o * 4096] = rp[(size_t)o * 4096] + acc[o];
}

// Fused conv4 + VQ (R14). LDS-staged wT4/e2/emb-chunks; BHWD gather.
__global__ __launch_bounds__(256) void conv4_vq(
    const float* __restrict__ h, const float* __restrict__ wT4,
    const float* __restrict__ b4, const float* __restrict__ emb,
    const float* __restrict__ e2, float* __restrict__ out) {
  __shared__ __align__(16) float wlds[128 * 64];
  __shared__ __align__(16) float elds[64 * 64];
  __shared__ float e2lds[512];

  const int tid = threadIdx.x;
  for (int i = tid; i < 128 * 64; i += 256) wlds[i] = wT4[i];
  for (int i = tid; i < 512; i += 256) e2lds[i] = e2[i];
  __syncthreads();

  const int pid = blockIdx.x * 256 + tid;
  const int n = pid >> 12, px = pid & 4095;
  const float* ip = h + (size_t)n * 128 * 4096 + px;
  float z[64];
#pragma unroll
  for (int d = 0; d < 64; ++d) z[d] = b4[d];
#pragma unroll 2
  for (int i = 0; i < 128; ++i) {
    float v = fmaxf(ip[(size_t)i * 4096], 0.f);
    const float4* w4 = (const float4*)(wlds + i * 64);
#pragma unroll
    for (int q = 0; q < 16; ++q) {
      float4 wv = w4[q];
      z[4 * q + 0] = fmaf(wv.x, v, z[4 * q + 0]);
      z[4 * q + 1] = fmaf(wv.y, v, z[4 * q + 1]);
      z[4 * q + 2] = fmaf(wv.z, v, z[4 * q + 2]);
      z[4 * q + 3] = fmaf(wv.w, v, z[4 * q + 3]);
    }
  }
  float z2 = 0.f;
#pragma unroll
  for (int d = 0; d < 64; ++d) z2 = fmaf(z[d], z[d], z2);

  float best = __builtin_inff();
  int bidx = 0;
  for (int r0 = 0; r0 < 512; r0 += 64) {
    __syncthreads();
    for (int i = tid; i < 64 * 64; i += 256) elds[i] = emb[(size_t)r0 * 64 + i];
    __syncthreads();
#pragma unroll 1
    for (int r = 0; r < 64; ++r) {
      const float4* e4 = (const float4*)(elds + r * 64);
      float p0 = 0.f, p1 = 0.f, p2 = 0.f, p3 = 0.f;
#pragma unroll
      for (int q = 0; q < 16; ++q) {
        float4 ev = e4[q];
        p0 = fmaf(ev.x, z[4 * q + 0], p0);
        p1 = fmaf(ev.y, z[4 * q + 1], p1);
        p2 = fmaf(ev.z, z[4 * q + 2], p2);
        p3 = fmaf(ev.w, z[4 * q + 3], p3);
      }
      float dot = (p0 + p1) + (p2 + p3);
      float dist = (z2 - 2.f * dot) + e2lds[r0 + r];
      if (dist < best) { best = dist; bidx = r0 + r; }
    }
  }

  const float4* eb = (const float4*)(emb + (size_t)bidx * 64);
  float4* op = (float4*)(out + (size_t)pid * 64);
#pragma unroll
  for (int q = 0; q < 16; ++q) op[q] = eb[q];
}

extern "C" void kernel_launch(void* const* d_in, const int* in_sizes, int n_in,
                              void* d_out, int out_size, void* d_ws, size_t ws_size,
                              hipStream_t stream) {
  const float* x    = (const float*)d_in[0];
  const float* w1   = (const float*)d_in[1];
  const float* b1   = (const float*)d_in[2];
  const float* w2   = (const float*)d_in[3];
  const float* b2   = (const float*)d_in[4];
  const float* w3   = (const float*)d_in[5];
  const float* b3   = (const float*)d_in[6];
  const float* r1w1 = (const float*)d_in[7];
  const float* r1b1 = (const float*)d_in[8];
  const float* r1w2 = (const float*)d_in[9];
  const float* r1b2 = (const float*)d_in[10];
  const float* r2w1 = (const float*)d_in[11];
  const float* r2b1 = (const float*)d_in[12];
  const float* r2w2 = (const float*)d_in[13];
  const float* r2b2 = (const float*)d_in[14];
  const float* w4   = (const float*)d_in[15];
  const float* b4   = (const float*)d_in[16];
  const float* emb  = (const float*)d_in[17];

  char* ws = (char*)d_ws;
  float* wT1   = (float*)ws;          // 1024
  float* wT2   = wT1 + 1024;          // 131072
  float* wTr1b = wT2 + 131072;        // 4096
  float* wTr2b = wTr1b + 4096;        // 4096
  float* wT4   = wTr2b + 4096;        // 8192
  float* e2v   = wT4 + 8192;          // 512
  short* c3h   = (short*)(e2v + 512); // conv3: 147456 shorts x3
  short* c3m   = c3h + 147456;
  short* c3l   = c3m + 147456;
  short* r1h   = c3l + 147456;        // res1: 36864 x3
  short* r1m   = r1h + 36864;
  short* r1l   = r1m + 36864;
  short* r2h   = r1l + 36864;         // res2: 36864 x3
  short* r2m   = r2h + 36864;
  short* r2l   = r2m + 36864;

  const size_t WOFF = 3ull << 20;     // 3 MiB (weights ~2.1 MB)
  const size_t SZ_A = 4194304ull;     // 64ch*128*128*4 (h1/h3/h5)
  const size_t SZ_B = 2097152ull;     // 128ch*64*64*4  (h2/h4)
  const size_t SZ_C = 524288ull;      // 32ch*64*64*4   (t32)
  const size_t PER_IMG = SZ_A + SZ_B + SZ_C;
  int NB = 64;
  while (NB > 1 && WOFF + (size_t)NB * PER_IMG > ws_size) NB >>= 1;

  char* bufs = ws + WOFF;
  float* A  = (float*)bufs;
  float* B_ = (float*)(bufs + (size_t)NB * SZ_A);
  float* C_ = (float*)(bufs + (size_t)NB * (SZ_A + SZ_B));

  auto blk = [](int tot) { return (tot + 255) / 256; };
  repack_k<64> <<<blk(1024),   256, 0, stream>>>(w1,   wT1,   1024);
  repack_k<128><<<blk(131072), 256, 0, stream>>>(w2,   wT2,   131072);
  repack_k<128><<<blk(4096),   256, 0, stream>>>(r1w2, wTr1b, 4096);
  repack_k<128><<<blk(4096),   256, 0, stream>>>(r2w2, wTr2b, 4096);
  repack_k<64> <<<blk(8192),   256, 0, stream>>>(w4,   wT4,   8192);
  repack_mf3<128, 128><<<blk(147456), 256, 0, stream>>>(w3, c3h, c3m, c3l);
  repack_mf3<32, 128> <<<blk(36864),  256, 0, stream>>>(r1w1, r1h, r1m, r1l);
  repack_mf3<32, 128> <<<blk(36864),  256, 0, stream>>>(r2w1, r2h, r2m, r2l);
  e2_k<<<2, 256, 0, stream>>>(emb, e2v);

  for (int n0 = 0; n0 < 64; n0 += NB) {
    const int nb = (64 - n0 < NB) ? (64 - n0) : NB;
    const float* xc = x + (size_t)n0 * 65536;               // (nb,1,256,256)
    float* oc = (float*)d_out + (size_t)n0 * 4096 * 64;     // BHWD chunk base

    // conv1 (R14): 1px direct
    conv_direct<1, 64, 4, 2, 1, 1, 256, 256, false, true>
        <<<dim3(64, nb), 256, 0, stream>>>(xc, wT1, b1, A);
    // conv2 (R14): 1px direct, full OC=128
    conv_direct<64, 128, 4, 2, 1, 4, 128, 128, false, true>
        <<<dim3(16, nb), 256, 0, stream>>>(A, wT2, b2, B_);
    // conv3: MFMA 3-limb 6-pass, OC=128 (MT=8)
    conv_mf3<8, false><<<dim3(32, nb), 256, 0, stream>>>(
        B_, c3h, c3m, c3l, b3, A);
    // res1 3x3: MFMA 3-limb 6-pass, OC=32 (MT=2), relu-in
    conv_mf3<2, true><<<dim3(32, nb), 256, 0, stream>>>(
        A, r1h, r1m, r1l, r1b1, C_);
    conv1x1_res<32, 128><<<nb * 16, 256, 0, stream>>>(C_, wTr1b, r1b2, A, B_);
    // res2 3x3
    conv_mf3<2, true><<<dim3(32, nb), 256, 0, stream>>>(
        B_, r2h, r2m, r2l, r2b1, C_);
    conv1x1_res<32, 128><<<nb * 16, 256, 0, stream>>>(C_, wTr2b, r2b2, B_, A);
    // conv4 + VQ (R14)
    conv4_vq<<<nb * 16, 256, 0, stream>>>(A, wT4, b4, emb, e2v, oc);
  }
}

// Round 23
// 3141.778 us; speedup vs baseline: 1.9363x; 1.0525x over previous
//
#include <hip/hip_runtime.h>

#define TDIM 16

typedef unsigned short u16;
typedef __attribute__((ext_vector_type(8))) short bf16x8;
typedef __attribute__((ext_vector_type(4))) float f32x4;

__device__ __forceinline__ float b2f(u16 u) {
  return __uint_as_float(((unsigned)u) << 16);
}
__device__ __forceinline__ u16 f2bf(float f) {
  unsigned u = __float_as_uint(f);
  unsigned r = 0x7FFFu + ((u >> 16) & 1u);
  return (u16)((u + r) >> 16);
}

// repack OIHW (fp32) -> [ic*K*K][oc]
template<int OC>
__global__ __launch_bounds__(256) void repack_k(const float* __restrict__ w,
                                                float* __restrict__ wT, int tot) {
  int i = blockIdx.x * 256 + threadIdx.x;
  if (i >= tot) return;
  int row = i / OC, oc = i - row * OC;          // row = ic*K*K + ky*K + kx
  wT[i] = w[(size_t)oc * (size_t)(tot / OC) + row];
}

// repack OIHW(3x3) fp32 -> 3 bf16 limbs, layout [pos][ic-chunk][oc][32]
template<int OC, int IC>
__global__ __launch_bounds__(256) void repack_mf3(const float* __restrict__ w,
                                                  short* __restrict__ hi,
                                                  short* __restrict__ mid,
                                                  short* __restrict__ lo) {
  constexpr int NCH = IC / 32;
  int tot = OC * IC * 9;
  int i = blockIdx.x * 256 + threadIdx.x;
  if (i >= tot) return;
  int icl = i & 31;
  int rem = i >> 5;
  int oc = rem % OC; rem /= OC;
  int ch = rem % NCH;
  int pos = rem / NCH;
  int ic = ch * 32 + icl;
  int ky = pos / 3, kx = pos - ky * 3;
  float v = w[((size_t)(oc * IC + ic) * 3 + ky) * 3 + kx];
  u16 h = f2bf(v);
  float t1 = v - b2f(h);
  u16 m = f2bf(t1);
  float t2 = t1 - b2f(m);
  hi[i] = (short)h;
  mid[i] = (short)m;
  lo[i] = (short)f2bf(t2);
}

// repack conv2 OIHW(128,64,4,4) -> 3 limbs, layout [ky][ch8][oc][kx*8+icl]
__global__ __launch_bounds__(256) void repack_mf2(const float* __restrict__ w,
                                                  short* __restrict__ hi,
                                                  short* __restrict__ mid,
                                                  short* __restrict__ lo) {
  int i = blockIdx.x * 256 + threadIdx.x;
  if (i >= 131072) return;
  int icl = i & 7;
  int kx = (i >> 3) & 3;
  int oc = (i >> 5) & 127;
  int t = i >> 12;
  int ch = t & 7, ky = t >> 3;
  int ic = ch * 8 + icl;
  float v = w[((size_t)(oc * 64 + ic) * 4 + ky) * 4 + kx];
  u16 h = f2bf(v);
  float t1 = v - b2f(h);
  u16 m = f2bf(t1);
  float t2 = t1 - b2f(m);
  hi[i] = (short)h;
  mid[i] = (short)m;
  lo[i] = (short)f2bf(t2);
}

// e2[r] = sum_f32 e*e
__global__ __launch_bounds__(256) void e2_k(const float* __restrict__ emb,
                                            float* __restrict__ e2) {
  int r = blockIdx.x * 256 + threadIdx.x;
  if (r >= 512) return;
  float s = 0.f;
#pragma unroll
  for (int d = 0; d < 64; ++d) s = fmaf(emb[r * 64 + d], emb[r * 64 + d], s);
  e2[r] = s;
}

// MFMA 3-limb bf16 6-pass 3x3 conv (IC=128, 64x64, pad 1, stride 1). (R22)
template<int MT, bool RELU_IN>
__global__ __launch_bounds__(256, 2) void conv_mf3(
    const float* __restrict__ in, const short* __restrict__ wh,
    const short* __restrict__ wm, const short* __restrict__ wl,
    const float* __restrict__ bias, float* __restrict__ out) {
  constexpr int OC = MT * 16;
  __shared__ __align__(16) short xh[10560];   // [4 rows][66 cols][40 stride]
  __shared__ __align__(16) short xm[10560];
  __shared__ __align__(16) short xl[10560];

  const int tid = threadIdx.x;
  const int n = blockIdx.y;
  const int r0 = blockIdx.x * 2;
  const int wv = tid >> 6, lane = tid & 63;
  const int nlo = lane & 15, kg = lane >> 4;

  f32x4 acc[MT][2];
#pragma unroll
  for (int mt = 0; mt < MT; ++mt)
#pragma unroll
    for (int ti = 0; ti < 2; ++ti) acc[mt][ti] = (f32x4){0.f, 0.f, 0.f, 0.f};

#pragma unroll 1
  for (int ch = 0; ch < 4; ++ch) {
    __syncthreads();
    for (int i = tid; i < 8448; i += 256) {
      int c = i % 66;
      int rem = i / 66;
      int lr = rem & 3, icl = rem >> 2;
      int gr = r0 - 1 + lr, gc = c - 1;
      float v = 0.f;
      if (gr >= 0 && gr < 64 && gc >= 0 && gc < 64)
        v = in[((size_t)(n * 128 + ch * 32 + icl) * 64 + gr) * 64 + gc];
      if (RELU_IN) v = fmaxf(v, 0.f);
      u16 h = f2bf(v);
      float t1 = v - b2f(h);
      u16 m = f2bf(t1);
      float t2 = t1 - b2f(m);
      int a = (lr * 66 + c) * 40 + icl;
      xh[a] = (short)h;
      xm[a] = (short)m;
      xl[a] = (short)f2bf(t2);
    }
    __syncthreads();

#pragma unroll 1
    for (int pos = 0; pos < 9; ++pos) {
      const int ky = pos / 3, kx = pos - ky * 3;
      bf16x8 bh[2], bm[2], bl[2];
#pragma unroll
      for (int ti = 0; ti < 2; ++ti) {
        int t = wv * 2 + ti;
        int lr = (t >> 2) + ky;
        int c = (t & 3) * 16 + nlo + kx;
        int a = (lr * 66 + c) * 40 + kg * 8;
        bh[ti] = *(const bf16x8*)(xh + a);
        bm[ti] = *(const bf16x8*)(xm + a);
        bl[ti] = *(const bf16x8*)(xl + a);
      }
      const size_t wo =
          ((size_t)(pos * 4 + ch) * OC + nlo) * 32 + (size_t)kg * 8;
#pragma unroll
      for (int mt = 0; mt < MT; ++mt) {
        const size_t o = wo + (size_t)mt * 16 * 32;
        bf16x8 AH = *(const bf16x8*)(wh + o);
        bf16x8 AM = *(const bf16x8*)(wm + o);
        bf16x8 AL = *(const bf16x8*)(wl + o);
#pragma unroll
        for (int ti = 0; ti < 2; ++ti) {
          acc[mt][ti] = __builtin_amdgcn_mfma_f32_16x16x32_bf16(
              AH, bh[ti], acc[mt][ti], 0, 0, 0);
          acc[mt][ti] = __builtin_amdgcn_mfma_f32_16x16x32_bf16(
              AH, bm[ti], acc[mt][ti], 0, 0, 0);
          acc[mt][ti] = __builtin_amdgcn_mfma_f32_16x16x32_bf16(
              AM, bh[ti], acc[mt][ti], 0, 0, 0);
          acc[mt][ti] = __builtin_amdgcn_mfma_f32_16x16x32_bf16(
              AH, bl[ti], acc[mt][ti], 0, 0, 0);
          acc[mt][ti] = __builtin_amdgcn_mfma_f32_16x16x32_bf16(
              AL, bh[ti], acc[mt][ti], 0, 0, 0);
          acc[mt][ti] = __builtin_amdgcn_mfma_f32_16x16x32_bf16(
              AM, bm[ti], acc[mt][ti], 0, 0, 0);
        }
      }
    }
  }

#pragma unroll
  for (int mt = 0; mt < MT; ++mt)
#pragma unroll
    for (int ti = 0; ti < 2; ++ti) {
      int t = wv * 2 + ti;
      int grow = r0 + (t >> 2);
      int px = (t & 3) * 16 + nlo;
#pragma unroll
      for (int j = 0; j < 4; ++j) {
        int oc = mt * 16 + kg * 4 + j;
        out[((size_t)(n * OC + oc) * 64 + grow) * 64 + px] =
            acc[mt][ti][j] + bias[oc];
      }
    }
}

// MFMA 3-limb 6-pass conv2: IC=64, OC=128, K=4, S=2, PAD=1, in 128x128,
// out 64x64. k-dim = (kx, ic8): K=32 per MFMA. 2 out rows/block, 4 waves,
// each wave 2 px-tiles x 8 m-tiles. x limbs in LDS [6 rows][132 cols][8 ic];
// w limbs from global layout [ky][ch8][oc][kx*8+icl]. relu epilogue.
__global__ __launch_bounds__(256, 2) void conv_mf2(
    const float* __restrict__ in, const short* __restrict__ wh,
    const short* __restrict__ wm, const short* __restrict__ wl,
    const float* __restrict__ bias, float* __restrict__ out) {
  __shared__ __align__(16) short xh[6336];   // [6][132][8]
  __shared__ __align__(16) short xm[6336];
  __shared__ __align__(16) short xl[6336];

  const int tid = threadIdx.x;
  const int n = blockIdx.y;
  const int r0 = blockIdx.x * 2;             // output row base
  const int wv = tid >> 6, lane = tid & 63;
  const int nlo = lane & 15, kg = lane >> 4;

  f32x4 acc[8][2];
#pragma unroll
  for (int mt = 0; mt < 8; ++mt)
#pragma unroll
    for (int ti = 0; ti < 2; ++ti) acc[mt][ti] = (f32x4){0.f, 0.f, 0.f, 0.f};

#pragma unroll 1
  for (int ch = 0; ch < 8; ++ch) {
    __syncthreads();
    // stage rows 2r0-1..2r0+4, cols -1..130, ic ch*8..+8 (3 limbs)
    for (int i = tid; i < 6336; i += 256) {
      int c = i % 132;
      int rem = i / 132;
      int lr = rem % 6, icl = rem / 6;
      int gr = 2 * r0 - 1 + lr, gc = c - 1;
      float v = 0.f;
      if (gr >= 0 && gr < 128 && gc >= 0 && gc < 128)
        v = in[((size_t)(n * 64 + ch * 8 + icl) * 128 + gr) * 128 + gc];
      u16 h = f2bf(v);
      float t1 = v - b2f(h);
      u16 m = f2bf(t1);
      float t2 = t1 - b2f(m);
      int a = (lr * 132 + c) * 8 + icl;
      xh[a] = (short)h;
      xm[a] = (short)m;
      xl[a] = (short)f2bf(t2);
    }
    __syncthreads();

#pragma unroll 1
    for (int ky = 0; ky < 4; ++ky) {
      bf16x8 bh[2], bm[2], bl[2];
#pragma unroll
      for (int ti = 0; ti < 2; ++ti) {
        int t = wv * 2 + ti;
        int lr = 2 * (t >> 2) + ky;                      // 0..5
        int px = (t & 3) * 16 + nlo;
        int cidx = 2 * px + kg;                          // 0..129
        int a = (lr * 132 + cidx) * 8;
        bh[ti] = *(const bf16x8*)(xh + a);
        bm[ti] = *(const bf16x8*)(xm + a);
        bl[ti] = *(const bf16x8*)(xl + a);
      }
      const size_t wo = ((size_t)(ky * 8 + ch) * 128 + nlo) * 32 +
                        (size_t)kg * 8;
#pragma unroll
      for (int mt = 0; mt < 8; ++mt) {
        const size_t o = wo + (size_t)mt * 16 * 32;
        bf16x8 AH = *(const bf16x8*)(wh + o);
        bf16x8 AM = *(const bf16x8*)(wm + o);
        bf16x8 AL = *(const bf16x8*)(wl + o);
#pragma unroll
        for (int ti = 0; ti < 2; ++ti) {
          acc[mt][ti] = __builtin_amdgcn_mfma_f32_16x16x32_bf16(
              AH, bh[ti], acc[mt][ti], 0, 0, 0);
          acc[mt][ti] = __builtin_amdgcn_mfma_f32_16x16x32_bf16(
              AH, bm[ti], acc[mt][ti], 0, 0, 0);
          acc[mt][ti] = __builtin_amdgcn_mfma_f32_16x16x32_bf16(
              AM, bh[ti], acc[mt][ti], 0, 0, 0);
          acc[mt][ti] = __builtin_amdgcn_mfma_f32_16x16x32_bf16(
              AH, bl[ti], acc[mt][ti], 0, 0, 0);
          acc[mt][ti] = __builtin_amdgcn_mfma_f32_16x16x32_bf16(
              AL, bh[ti], acc[mt][ti], 0, 0, 0);
          acc[mt][ti] = __builtin_amdgcn_mfma_f32_16x16x32_bf16(
              AM, bm[ti], acc[mt][ti], 0, 0, 0);
        }
      }
    }
  }

  // epilogue: relu(acc + bias); D col=lane&15 (px), row=(lane>>4)*4+j (oc)
#pragma unroll
  for (int mt = 0; mt < 8; ++mt)
#pragma unroll
    for (int ti = 0; ti < 2; ++ti) {
      int t = wv * 2 + ti;
      int grow = r0 + (t >> 2);
      int px = (t & 3) * 16 + nlo;
#pragma unroll
      for (int j = 0; j < 4; ++j) {
        int oc = mt * 16 + kg * 4 + j;
        out[((size_t)(n * 128 + oc) * 64 + grow) * 64 + px] =
            fmaxf(acc[mt][ti][j] + bias[oc], 0.f);
      }
    }
}

// 1-px direct conv (R14): fp32, bias in acc, LDS weights, full OC.
template<int IC, int OC, int K, int S, int PAD, int CCH, int IH, int IW,
         bool RELU_IN, bool RELU_OUT>
__global__ __launch_bounds__(256) void conv_direct(
    const float* __restrict__ in, const float* __restrict__ wT,
    const float* __restrict__ bias, float* __restrict__ out) {
  constexpr int OH = (IH + 2 * PAD - K) / S + 1;
  constexpr int OW = OH;
  constexpr int RS = (TDIM - 1) * S + K;
  constexpr int CS = RS;
  constexpr int TX = OW / TDIM;
  constexpr int TOT = CCH * RS * CS;
  constexpr int WSLAB = CCH * K * K * OC;

  __shared__ __align__(16) float lds[TOT];
  __shared__ __align__(16) float wlds[WSLAB];

  const int tid = threadIdx.x;
  const int n = blockIdx.y;
  const int tile = blockIdx.x;
  const int oh0 = (tile / TX) * TDIM;
  const int ow0 = (tile % TX) * TDIM;
  const int ty = tid >> 4, tx = tid & 15;
  const int oh = oh0 + ty, ow = ow0 + tx;

  float acc[OC];
#pragma unroll
  for (int oc = 0; oc < OC; ++oc) acc[oc] = bias[oc];

  for (int ic0 = 0; ic0 < IC; ic0 += CCH) {
    __syncthreads();
    for (int i = tid; i < TOT; i += 256) {
      int c = i / (RS * CS);
      int rem = i - c * (RS * CS);
      int r = rem / CS;
      int col = rem - r * CS;
      int gr = oh0 * S + r - PAD;
      int gc = ow0 * S + col - PAD;
      float v = 0.f;
      if (gr >= 0 && gr < IH && gc >= 0 && gc < IW) {
        v = in[((size_t)(n * IC + ic0 + c) * IH + gr) * IW + gc];
        if (RELU_IN) v = fmaxf(v, 0.f);
      }
      lds[i] = v;
    }
    {
      const float* wsrc = wT + (size_t)ic0 * (K * K * OC);
      for (int i = tid; i < WSLAB; i += 256) wlds[i] = wsrc[i];
    }
    __syncthreads();
#pragma unroll 1
    for (int c = 0; c < CCH; ++c) {
#pragma unroll
      for (int ky = 0; ky < K; ++ky)
#pragma unroll
        for (int kx = 0; kx < K; ++kx) {
          float v = lds[(c * RS + ty * S + ky) * CS + tx * S + kx];
          const float4* w4 =
              (const float4*)(wlds + (c * K * K + ky * K + kx) * OC);
#pragma unroll
          for (int q = 0; q < OC / 4; ++q) {
            float4 wv = w4[q];
            acc[4 * q + 0] = fmaf(wv.x, v, acc[4 * q + 0]);
            acc[4 * q + 1] = fmaf(wv.y, v, acc[4 * q + 1]);
            acc[4 * q + 2] = fmaf(wv.z, v, acc[4 * q + 2]);
            acc[4 * q + 3] = fmaf(wv.w, v, acc[4 * q + 3]);
          }
        }
    }
  }

#pragma unroll
  for (int oc = 0; oc < OC; ++oc) {
    float r = acc[oc];
    if (RELU_OUT) r = fmaxf(r, 0.f);
    out[((size_t)(n * OC + oc) * OH + oh) * OW + ow] = r;
  }
}

// 1x1 conv (relu on read) + residual add, fp32; weights staged in LDS. (R14)
template<int IC, int OC>
__global__ __launch_bounds__(256) void conv1x1_res(
    const float* __restrict__ in, const float* __restrict__ wT,
    const float* __restrict__ bias, const float* __restrict__ res,
    float* __restrict__ out) {
  __shared__ __align__(16) float wlds[IC * OC];
  for (int i = threadIdx.x; i < IC * OC; i += 256) wlds[i] = wT[i];
  __syncthreads();

  const int pid = blockIdx.x * 256 + threadIdx.x;
  const int n = pid >> 12, px = pid & 4095;
  const float* ip = in + (size_t)n * IC * 4096 + px;
  float acc[OC];
#pragma unroll
  for (int o = 0; o < OC; ++o) acc[o] = bias[o];
#pragma unroll 4
  for (int i = 0; i < IC; ++i) {
    float v = fmaxf(ip[(size_t)i * 4096], 0.f);
    const float4* w4 = (const float4*)(wlds + i * OC);
#pragma unroll
    for (int q = 0; q < OC / 4; ++q) {
      float4 wv = w4[q];
      acc[4 * q + 0] = fmaf(wv.x, v, acc[4 * q + 0]);
      acc[4 * q + 1] = fmaf(wv.y, v, acc[4 * q + 1]);
      acc[4 * q + 2] = fmaf(wv.z, v, acc[4 * q + 2]);
      acc[4 * q + 3] = fmaf(wv.w, v, acc[4 * q + 3]);
    }
  }
  const float* rp = res + (size_t)n * OC * 4096 + px;
  float* op = out + (size_t)n * OC * 4096 + px;
#pragma unroll
  for (int o = 0; o < OC; ++o) op[(size_t)o * 4096] = rp[(size_t)o * 4096] + acc[o];
}

// Fused conv4 + VQ (R14). LDS-staged wT4/e2/emb-chunks; BHWD gather.
__global__ __launch_bounds__(256) void conv4_vq(
    const float* __restrict__ h, const float* __restrict__ wT4,
    const float* __restrict__ b4, const float* __restrict__ emb,
    const float* __restrict__ e2, float* __restrict__ out) {
  __shared__ __align__(16) float wlds[128 * 64];
  __shared__ __align__(16) float elds[64 * 64];
  __shared__ float e2lds[512];

  const int tid = threadIdx.x;
  for (int i = tid; i < 128 * 64; i += 256) wlds[i] = wT4[i];
  for (int i = tid; i < 512; i += 256) e2lds[i] = e2[i];
  __syncthreads();

  const int pid = blockIdx.x * 256 + tid;
  const int n = pid >> 12, px = pid & 4095;
  const float* ip = h + (size_t)n * 128 * 4096 + px;
  float z[64];
#pragma unroll
  for (int d = 0; d < 64; ++d) z[d] = b4[d];
#pragma unroll 2
  for (int i = 0; i < 128; ++i) {
    float v = fmaxf(ip[(size_t)i * 4096], 0.f);
    const float4* w4 = (const float4*)(wlds + i * 64);
#pragma unroll
    for (int q = 0; q < 16; ++q) {
      float4 wv = w4[q];
      z[4 * q + 0] = fmaf(wv.x, v, z[4 * q + 0]);
      z[4 * q + 1] = fmaf(wv.y, v, z[4 * q + 1]);
      z[4 * q + 2] = fmaf(wv.z, v, z[4 * q + 2]);
      z[4 * q + 3] = fmaf(wv.w, v, z[4 * q + 3]);
    }
  }
  float z2 = 0.f;
#pragma unroll
  for (int d = 0; d < 64; ++d) z2 = fmaf(z[d], z[d], z2);

  float best = __builtin_inff();
  int bidx = 0;
  for (int r0 = 0; r0 < 512; r0 += 64) {
    __syncthreads();
    for (int i = tid; i < 64 * 64; i += 256) elds[i] = emb[(size_t)r0 * 64 + i];
    __syncthreads();
#pragma unroll 1
    for (int r = 0; r < 64; ++r) {
      const float4* e4 = (const float4*)(elds + r * 64);
      float p0 = 0.f, p1 = 0.f, p2 = 0.f, p3 = 0.f;
#pragma unroll
      for (int q = 0; q < 16; ++q) {
        float4 ev = e4[q];
        p0 = fmaf(ev.x, z[4 * q + 0], p0);
        p1 = fmaf(ev.y, z[4 * q + 1], p1);
        p2 = fmaf(ev.z, z[4 * q + 2], p2);
        p3 = fmaf(ev.w, z[4 * q + 3], p3);
      }
      float dot = (p0 + p1) + (p2 + p3);
      float dist = (z2 - 2.f * dot) + e2lds[r0 + r];
      if (dist < best) { best = dist; bidx = r0 + r; }
    }
  }

  const float4* eb = (const float4*)(emb + (size_t)bidx * 64);
  float4* op = (float4*)(out + (size_t)pid * 64);
#pragma unroll
  for (int q = 0; q < 16; ++q) op[q] = eb[q];
}

extern "C" void kernel_launch(void* const* d_in, const int* in_sizes, int n_in,
                              void* d_out, int out_size, void* d_ws, size_t ws_size,
                              hipStream_t stream) {
  const float* x    = (const float*)d_in[0];
  const float* w1   = (const float*)d_in[1];
  const float* b1   = (const float*)d_in[2];
  const float* w2   = (const float*)d_in[3];
  const float* b2   = (const float*)d_in[4];
  const float* w3   = (const float*)d_in[5];
  const float* b3   = (const float*)d_in[6];
  const float* r1w1 = (const float*)d_in[7];
  const float* r1b1 = (const float*)d_in[8];
  const float* r1w2 = (const float*)d_in[9];
  const float* r1b2 = (const float*)d_in[10];
  const float* r2w1 = (const float*)d_in[11];
  const float* r2b1 = (const float*)d_in[12];
  const float* r2w2 = (const float*)d_in[13];
  const float* r2b2 = (const float*)d_in[14];
  const float* w4   = (const float*)d_in[15];
  const float* b4   = (const float*)d_in[16];
  const float* emb  = (const float*)d_in[17];

  char* ws = (char*)d_ws;
  float* wT1   = (float*)ws;          // 1024
  float* wTr1b = wT1 + 1024;          // 4096
  float* wTr2b = wTr1b + 4096;        // 4096
  float* wT4   = wTr2b + 4096;        // 8192
  float* e2v   = wT4 + 8192;          // 512
  short* c3h   = (short*)(e2v + 512); // conv3: 147456 x3
  short* c3m   = c3h + 147456;
  short* c3l   = c3m + 147456;
  short* r1h   = c3l + 147456;        // res1: 36864 x3
  short* r1m   = r1h + 36864;
  short* r1l   = r1m + 36864;
  short* r2h   = r1l + 36864;         // res2: 36864 x3
  short* r2m   = r2h + 36864;
  short* r2l   = r2m + 36864;
  short* w2h   = r2l + 36864;         // conv2: 131072 x3
  short* w2m   = w2h + 131072;
  short* w2l   = w2m + 131072;

  const size_t WOFF = 3ull << 20;     // 3 MiB (weights ~2.2 MB)
  const size_t SZ_A = 4194304ull;     // 64ch*128*128*4 (h1/h3/h5)
  const size_t SZ_B = 2097152ull;     // 128ch*64*64*4  (h2/h4)
  const size_t SZ_C = 524288ull;      // 32ch*64*64*4   (t32)
  const size_t PER_IMG = SZ_A + SZ_B + SZ_C;
  int NB = 64;
  while (NB > 1 && WOFF + (size_t)NB * PER_IMG > ws_size) NB >>= 1;

  char* bufs = ws + WOFF;
  float* A  = (float*)bufs;
  float* B_ = (float*)(bufs + (size_t)NB * SZ_A);
  float* C_ = (float*)(bufs + (size_t)NB * (SZ_A + SZ_B));

  auto blk = [](int tot) { return (tot + 255) / 256; };
  repack_k<64> <<<blk(1024),   256, 0, stream>>>(w1,   wT1,   1024);
  repack_k<128><<<blk(4096),   256, 0, stream>>>(r1w2, wTr1b, 4096);
  repack_k<128><<<blk(4096),   256, 0, stream>>>(r2w2, wTr2b, 4096);
  repack_k<64> <<<blk(8192),   256, 0, stream>>>(w4,   wT4,   8192);
  repack_mf2<<<blk(131072), 256, 0, stream>>>(w2, w2h, w2m, w2l);
  repack_mf3<128, 128><<<blk(147456), 256, 0, stream>>>(w3, c3h, c3m, c3l);
  repack_mf3<32, 128> <<<blk(36864),  256, 0, stream>>>(r1w1, r1h, r1m, r1l);
  repack_mf3<32, 128> <<<blk(36864),  256, 0, stream>>>(r2w1, r2h, r2m, r2l);
  e2_k<<<2, 256, 0, stream>>>(emb, e2v);

  for (int n0 = 0; n0 < 64; n0 += NB) {
    const int nb = (64 - n0 < NB) ? (64 - n0) : NB;
    const float* xc = x + (size_t)n0 * 65536;               // (nb,1,256,256)
    float* oc = (float*)d_out + (size_t)n0 * 4096 * 64;     // BHWD chunk base

    // conv1 (R14): 1px direct
    conv_direct<1, 64, 4, 2, 1, 1, 256, 256, false, true>
        <<<dim3(64, nb), 256, 0, stream>>>(xc, wT1, b1, A);
    // conv2: MFMA 3-limb 6-pass, stride-2 (k = kx x ic8)
    conv_mf2<<<dim3(32, nb), 256, 0, stream>>>(A, w2h, w2m, w2l, b2, B_);
    // conv3: MFMA 3-limb 6-pass, OC=128 (MT=8)
    conv_mf3<8, false><<<dim3(32, nb), 256, 0, stream>>>(
        B_, c3h, c3m, c3l, b3, A);
    // res1 3x3: MFMA 3-limb 6-pass, OC=32 (MT=2), relu-in
    conv_mf3<2, true><<<dim3(32, nb), 256, 0, stream>>>(
        A, r1h, r1m, r1l, r1b1, C_);
    conv1x1_res<32, 128><<<nb * 16, 256, 0, stream>>>(C_, wTr1b, r1b2, A, B_);
    // res2 3x3
    conv_mf3<2, true><<<dim3(32, nb), 256, 0, stream>>>(
        B_, r2h, r2m, r2l, r2b1, C_);
    conv1x1_res<32, 128><<<nb * 16, 256, 0, stream>>>(C_, wTr2b, r2b2, B_, A);
    // conv4 + VQ (R14)
    conv4_vq<<<nb * 16, 256, 0, stream>>>(A, wT4, b4, emb, e2v, oc);
  }
}